// Round 1
// 608.698 us; speedup vs baseline: 1.4051x; 1.4051x over previous
//
#include <hip/hip_runtime.h>
#include <type_traits>

// LSTMNet: B=1024, T=2048, H=64, NC=10, input_size=1.
// R15: fuse gate-update into the MFMA waves -> ONE barrier + ONE LDS round
// trip per step (was two of each + gbuf round trip).
//  - Wave w now computes ALL 4 gates for units 16w..16w+15 (B-frag staging
//    re-indexed: tile t_ = gate*4 + u4 instead of u4*4 + gate). Same 8
//    MFMA/wave/step; a cell's 4 gates land in one lane's acc regs.
//  - Batch row 0 -> A-row 0, batch row 1 -> A-row 4: C/D layout puts row 0
//    at quad0/reg0 and row 4 at quad1/reg0, so quads 0 and 1 update one
//    cell each with the SAME reg index in one instruction stream
//    (1 cell/lane, 32 lanes; no shuffles, no selects). Rows 1-3,5-15 stay 0.
//  - Activation arg scales (-log2e / -2log2e) pre-folded into W_hh/W_ih/bias.
// Precision: identical math modulo pre-scale; prev measured absmax 9.8e-4.
// Structure: 512 blocks x 256 thr (4 waves), 2 rows/block, 2 blocks/CU.

#define T_STEPS 2048
#define HID 64
#define NCLS 10
#define XCH 128   // x chunk length (steps)
#define ROWS 2    // batch rows per block

typedef short bf16x8 __attribute__((ext_vector_type(8)));
typedef float f32x4 __attribute__((ext_vector_type(4)));

__device__ __forceinline__ unsigned short f2bf(float f) {  // RNE f32->bf16
    unsigned u = __builtin_bit_cast(unsigned, f);
    u = u + 0x7FFFu + ((u >> 16) & 1u);
    return (unsigned short)(u >> 16);
}

__global__ __attribute__((amdgpu_flat_work_group_size(256, 256),
                          amdgpu_waves_per_eu(2, 2)))
void lstm_mfma_kernel(
    const float* __restrict__ x,      // [B, 1, T]
    const float* __restrict__ W_ih,   // [256, 1]
    const float* __restrict__ W_hh,   // [256, 64]
    const float* __restrict__ b_ih,   // [256]
    const float* __restrict__ b_hh,   // [256]
    const float* __restrict__ fc1_w,  // [64, 64]
    const float* __restrict__ fc1_b,  // [64]
    const float* __restrict__ fc2_w,  // [10, 64]
    const float* __restrict__ fc2_b,  // [10]
    float* __restrict__ out)          // [B, 10]
{
    const int tid  = threadIdx.x;
    const int lane = tid & 63;
    const int w    = tid >> 6;        // wave id = unit-chunk owner
    const int quad = lane >> 4;
    const int col  = lane & 15;
    const int row0 = blockIdx.x * ROWS;

    const float L2E = 1.4426950408889634f;

    // ---- LDS union: 32KB staging (dead after B-frag load) overlaps runtime ----
    __shared__ __align__(16) char smem[32768];
    short* whi = (short*)smem;                 // staging [0,32768)
    // runtime (valid only after the staging->register handoff sync):
    short (*abuf)[1088]        = (short(*)[1088])smem;              // 4352 B
    float (*xlds)[XCH + 4]     = (float(*)[XCH + 4])(smem + 4352);  // 1056 B
    float (*hf)[HID + 1]       = (float(*)[HID + 1])(smem + 5408);  //  520 B
    float (*r1buf)[HID + 1]    = (float(*)[HID + 1])(smem + 5928);  //  520 B

    // ---- stage: W_hh f32 -> bf16 fragments, pre-scaled per gate ----
    // tile t_ = g*4 + u4  => wave w (reading t_ = gg*4 + w) gets all 4 gates
    // for units 16w..16w+15.
    for (int idx = tid; idx < 256 * 64; idx += 256) {
        int r_ = idx >> 6;            // gate-major row 0..255
        int k  = idx & 63;
        int g = r_ >> 6, u = r_ & 63;
        float scg = (g == 2) ? -2.0f * L2E : -L2E;
        float f = W_hh[r_ * 64 + k] * scg;
        int u4 = u >> 4, n = u & 15;
        int kt = k >> 5, kq = (k & 31) >> 3, j = k & 7;
        int off = (((g * 4 + u4) * 2 + kt) * 64 + (kq * 16 + n)) * 8 + j;
        whi[off] = (short)f2bf(f);
    }
    __syncthreads();

    // ---- B fragments -> registers (wave w: tiles t_ = gg*4 + w) ----
    const int u0 = w * 16 + col;      // this lane's unit (cols of all 4 tiles)
    bf16x8 Bq[4][2];
    f32x4 biasC[4];
    #pragma unroll
    for (int gg = 0; gg < 4; ++gg) {
        int t_ = gg * 4 + w;
        #pragma unroll
        for (int kt = 0; kt < 2; ++kt) {
            int off = ((t_ * 2 + kt) * 64 + lane) * 8;
            Bq[gg][kt] = *(const bf16x8*)&whi[off];
            asm volatile("" : "+v"(Bq[gg][kt]));
        }
        float scg = (gg == 2) ? -2.0f * L2E : -L2E;
        float bs = (b_ih[gg * HID + u0] + b_hh[gg * HID + u0]) * scg;
        #pragma unroll
        for (int r = 0; r < 4; ++r) biasC[gg][r] = bs;
    }
    __syncthreads();   // all waves done READING staging; smem may be reused now

    // zero BOTH A buffers (rows never written stay zero = h0)
    for (int idx = tid; idx < 2 * 1088; idx += 256) ((short*)abuf)[idx] = 0;

    // ---- update constants: quad q<2 owns cell (batch row q, unit u0) ----
    float wih_u[4];
    #pragma unroll
    for (int gg = 0; gg < 4; ++gg) {
        float scg = (gg == 2) ? -2.0f * L2E : -L2E;
        wih_u[gg] = W_ih[gg * HID + u0] * scg;
    }
    float cc = 0.f, hl = 0.f;

    // invariant LDS coords
    const int ard0 = lane * 8 + (lane >> 4) * 8;          // A-read (kt=1 at +544)
    const int su   = (u0 >> 5) * 4 + ((u0 >> 3) & 3);     // k-chunk of unit u0
    // h-write: batch row q -> A-row 4*q  (byte row offset 8*(4q) shorts = 32q)
    const int awr  = su * 136 + 32 * quad + (u0 & 7);

    const float* xbase = x + (size_t)row0 * T_STEPS;
    __syncthreads();   // abuf zeroed

    auto step = [&](auto cur_c, int tl) __attribute__((always_inline)) {
        constexpr int CUR = decltype(cur_c)::value;
        constexpr int NXT = CUR ^ 1;

        // ---- all 4 gates for units 16w..16w+15, rows 0 (=b0) and 4 (=b1) ----
        bf16x8 A0 = *(const bf16x8*)&abuf[CUR][ard0];
        bf16x8 A1 = *(const bf16x8*)&abuf[CUR][ard0 + 544];

        f32x4 acc[4];
        #pragma unroll
        for (int gg = 0; gg < 4; ++gg)
            acc[gg] = __builtin_amdgcn_mfma_f32_16x16x32_bf16(A0, Bq[gg][0], biasC[gg], 0, 0, 0);
        #pragma unroll
        for (int gg = 0; gg < 4; ++gg)
            acc[gg] = __builtin_amdgcn_mfma_f32_16x16x32_bf16(A1, Bq[gg][1], acc[gg], 0, 0, 0);

        // ---- fused update: quad0 -> row0 (reg0), quad1 -> row4 (reg0) ----
        if (quad < 2) {
            float xv = xlds[quad][tl];
            // pre-scaled args: sigm gates hold -log2e*a, tanh gate -2log2e*a
            float a0 = fmaf(xv, wih_u[0], acc[0][0]);
            float a1 = fmaf(xv, wih_u[1], acc[1][0]);
            float a2 = fmaf(xv, wih_u[2], acc[2][0]);
            float a3 = fmaf(xv, wih_u[3], acc[3][0]);
            float ig = __builtin_amdgcn_rcpf(1.0f + __builtin_amdgcn_exp2f(a0));
            float fg = __builtin_amdgcn_rcpf(1.0f + __builtin_amdgcn_exp2f(a1));
            float gv = fmaf(2.0f, __builtin_amdgcn_rcpf(1.0f + __builtin_amdgcn_exp2f(a2)), -1.0f);
            float og = __builtin_amdgcn_rcpf(1.0f + __builtin_amdgcn_exp2f(a3));
            cc = fmaf(fg, cc, ig * gv);
            float ec = __builtin_amdgcn_exp2f(-2.8853900817779268f * cc);
            float th = fmaf(2.0f, __builtin_amdgcn_rcpf(1.0f + ec), -1.0f);
            hl = og * th;
            abuf[NXT][awr] = (short)f2bf(hl);
        }
        __syncthreads();   // new h-frags visible (single barrier per step)
    };

    #pragma unroll 1
    for (int tc = 0; tc < T_STEPS; tc += 2) {
        const int tl = tc & (XCH - 1);
        if (tl == 0) {
            // refill x chunk (prev barrier => old chunk fully consumed)
            if (tid < 16 * ROWS) {
                int xr = tid >> 4, tb = (tid & 15) * 8;
                const float* src = xbase + (size_t)xr * T_STEPS + tc + tb;
                float4 v0 = *(const float4*)(src);
                float4 v1 = *(const float4*)(src + 4);
                *(float4*)&xlds[xr][tb]     = v0;
                *(float4*)&xlds[xr][tb + 4] = v1;
            }
            __syncthreads();
        }
        step(std::integral_constant<int, 0>{}, tl);      // reads abuf[0], writes abuf[1]
        step(std::integral_constant<int, 1>{}, tl + 1);  // reads abuf[1], writes abuf[0]
    }

    // ---- epilogue: gather h, fc1 (relu) + fc2 ----
    if (quad < 2) hf[quad][u0] = hl;   // (row quad, unit 16w+col), all 4 waves
    __syncthreads();

    if (w < ROWS) {
        // thread -> (row = w, unit = lane)
        float s = fc1_b[lane];
        const float4* wrow = (const float4*)(fc1_w + lane * HID);
        #pragma unroll
        for (int j4 = 0; j4 < HID / 4; ++j4) {
            float4 wv = wrow[j4];
            s = fmaf(hf[w][j4 * 4 + 0], wv.x, s);
            s = fmaf(hf[w][j4 * 4 + 1], wv.y, s);
            s = fmaf(hf[w][j4 * 4 + 2], wv.z, s);
            s = fmaf(hf[w][j4 * 4 + 3], wv.w, s);
        }
        r1buf[w][lane] = fmaxf(s, 0.0f);
    }
    __syncthreads();

    if (tid < ROWS * NCLS) {
        int m = tid / NCLS, cls = tid % NCLS;
        float s = fc2_b[cls];
        const float* w2 = fc2_w + cls * HID;
        #pragma unroll
        for (int j = 0; j < HID; ++j) s = fmaf(r1buf[m][j], w2[j], s);
        out[(size_t)(row0 + m) * NCLS + cls] = s;
    }
}

extern "C" void kernel_launch(void* const* d_in, const int* in_sizes, int n_in,
                              void* d_out, int out_size, void* d_ws, size_t ws_size,
                              hipStream_t stream) {
    const float* x     = (const float*)d_in[0];
    const float* W_ih  = (const float*)d_in[1];
    const float* W_hh  = (const float*)d_in[2];
    const float* b_ih  = (const float*)d_in[3];
    const float* b_hh  = (const float*)d_in[4];
    const float* fc1_w = (const float*)d_in[5];
    const float* fc1_b = (const float*)d_in[6];
    const float* fc2_w = (const float*)d_in[7];
    const float* fc2_b = (const float*)d_in[8];
    float* out = (float*)d_out;

    dim3 grid(512);   // 1024 rows / 2 rows per block -> 2 blocks per CU
    dim3 block(256);  // 4 waves
    lstm_mfma_kernel<<<grid, block, 0, stream>>>(x, W_ih, W_hh, b_ih, b_hh,
                                                 fc1_w, fc1_b, fc2_w, fc2_b, out);
}

// Round 2
// 551.994 us; speedup vs baseline: 1.5495x; 1.1027x over previous
//
#include <hip/hip_runtime.h>
#include <type_traits>

// LSTMNet: B=1024, T=2048, H=64, NC=10, input_size=1.
// R16: R15 structure (fused gate-update, 1 barrier + 1 LDS round trip/step) +
//  - ROWS=4/block, 256 blocks -> 1 block/CU: rows {0,4,8,12} = (quad,reg0),
//    so ALL 4 quads update 1 cell/lane with the same reg index. Removes the
//    co-resident block's issue contention (R15 had 2 blocks/CU sharing SIMDs).
//  - kt-parallel MFMA: acc_lo=mfma(A0,B0,bias), acc_hi=mfma(A1,B1,0), scalar
//    add of reg0 -> removes one MFMA latency from the h-critical chain.
//  - v_cvt_pk_bf16_f32 (1 instr, RNE) replaces 3-op f2bf on the chain.
//  - kt1 A-offset 544->552 shorts (+16B, b128-aligned) to de-phase the two
//    concurrent ds_read_b128's bank groups (3.44e7 conflict cy = A-path).
// Precision: identical math to R15 (absmax 9.8e-4 measured).

#define T_STEPS 2048
#define HID 64
#define NCLS 10
#define XCH 128   // x chunk length (steps)
#define ROWS 4    // batch rows per block

typedef short bf16x8 __attribute__((ext_vector_type(8)));
typedef float f32x4 __attribute__((ext_vector_type(4)));

__device__ __forceinline__ unsigned short f2bf(float f) {  // RNE f32->bf16
    unsigned u = __builtin_bit_cast(unsigned, f);
    u = u + 0x7FFFu + ((u >> 16) & 1u);
    return (unsigned short)(u >> 16);
}

__global__ __attribute__((amdgpu_flat_work_group_size(256, 256)))
void lstm_mfma_kernel(
    const float* __restrict__ x,      // [B, 1, T]
    const float* __restrict__ W_ih,   // [256, 1]
    const float* __restrict__ W_hh,   // [256, 64]
    const float* __restrict__ b_ih,   // [256]
    const float* __restrict__ b_hh,   // [256]
    const float* __restrict__ fc1_w,  // [64, 64]
    const float* __restrict__ fc1_b,  // [64]
    const float* __restrict__ fc2_w,  // [10, 64]
    const float* __restrict__ fc2_b,  // [10]
    float* __restrict__ out)          // [B, 10]
{
    const int tid  = threadIdx.x;
    const int lane = tid & 63;
    const int w    = tid >> 6;        // wave id = unit-chunk owner
    const int quad = lane >> 4;       // = batch row within block (A-row 4*quad)
    const int col  = lane & 15;
    const int row0 = blockIdx.x * ROWS;

    const float L2E = 1.4426950408889634f;

    // ---- LDS union: 32KB staging (dead after B-frag load) overlaps runtime ----
    __shared__ __align__(16) char smem[32768];
    short* whi = (short*)smem;                 // staging [0,32768)
    // runtime (valid only after the staging->register handoff sync):
    short (*abuf)[1104]        = (short(*)[1104])smem;              // 4416 B
    float (*xlds)[XCH + 4]     = (float(*)[XCH + 4])(smem + 4416);  // 2112 B
    float (*hf)[HID + 1]       = (float(*)[HID + 1])(smem + 6528);  // 1040 B
    float (*r1buf)[HID + 1]    = (float(*)[HID + 1])(smem + 7568);  // 1040 B

    // ---- stage: W_hh f32 -> bf16 fragments, pre-scaled per gate ----
    // tile t_ = g*4 + u4  => wave w (reading t_ = gg*4 + w) gets all 4 gates
    // for units 16w..16w+15.
    for (int idx = tid; idx < 256 * 64; idx += 256) {
        int r_ = idx >> 6;            // gate-major row 0..255
        int k  = idx & 63;
        int g = r_ >> 6, u = r_ & 63;
        float scg = (g == 2) ? -2.0f * L2E : -L2E;
        float f = W_hh[r_ * 64 + k] * scg;
        int u4 = u >> 4, n = u & 15;
        int kt = k >> 5, kq = (k & 31) >> 3, j = k & 7;
        int off = (((g * 4 + u4) * 2 + kt) * 64 + (kq * 16 + n)) * 8 + j;
        whi[off] = (short)f2bf(f);
    }
    __syncthreads();

    // ---- B fragments -> registers (wave w: tiles t_ = gg*4 + w) ----
    const int u0 = w * 16 + col;      // this lane's unit (cols of all 4 tiles)
    bf16x8 Bq[4][2];
    f32x4 biasC[4];
    f32x4 zerov = {0.f, 0.f, 0.f, 0.f};
    #pragma unroll
    for (int gg = 0; gg < 4; ++gg) {
        int t_ = gg * 4 + w;
        #pragma unroll
        for (int kt = 0; kt < 2; ++kt) {
            int off = ((t_ * 2 + kt) * 64 + lane) * 8;
            Bq[gg][kt] = *(const bf16x8*)&whi[off];
            asm volatile("" : "+v"(Bq[gg][kt]));
        }
        float scg = (gg == 2) ? -2.0f * L2E : -L2E;
        float bs = (b_ih[gg * HID + u0] + b_hh[gg * HID + u0]) * scg;
        #pragma unroll
        for (int r = 0; r < 4; ++r) biasC[gg][r] = bs;
    }
    __syncthreads();   // all waves done READING staging; smem may be reused now

    // zero BOTH A buffers (rows never written stay zero = h0)
    for (int idx = tid; idx < 2 * 1104; idx += 256) ((short*)abuf)[idx] = 0;

    // ---- update constants: quad q owns cell (batch row q, unit u0) ----
    float wih_u[4];
    #pragma unroll
    for (int gg = 0; gg < 4; ++gg) {
        float scg = (gg == 2) ? -2.0f * L2E : -L2E;
        wih_u[gg] = W_ih[gg * HID + u0] * scg;
    }
    float cc = 0.f, hl = 0.f;

    // invariant LDS coords. A layout: addr(m,k)=552*(k>>5)+136*((k&31)>>3)+8m+(k&7)
    const int ard0 = lane * 8 + (lane >> 4) * 8;          // A-read kt0 (kt1 at +552)
    // h-write: batch row q -> A-row 4q (8m = 32*quad)
    const int awr  = (u0 >> 5) * 552 + ((u0 >> 3) & 3) * 136 + 32 * quad + (u0 & 7);

    const float* xbase = x + (size_t)row0 * T_STEPS;
    __syncthreads();   // abuf zeroed

    auto step = [&](auto cur_c, int tl) __attribute__((always_inline)) {
        constexpr int CUR = decltype(cur_c)::value;
        constexpr int NXT = CUR ^ 1;

        // ---- all 4 gates for units 16w..16w+15, rows {0,4,8,12} ----
        bf16x8 A0 = *(const bf16x8*)&abuf[CUR][ard0];
        bf16x8 A1 = *(const bf16x8*)&abuf[CUR][ard0 + 552];

        // kt-parallel: two independent MFMAs, combine reg0 with one add
        f32x4 alo[4], ahi[4];
        #pragma unroll
        for (int gg = 0; gg < 4; ++gg)
            alo[gg] = __builtin_amdgcn_mfma_f32_16x16x32_bf16(A0, Bq[gg][0], biasC[gg], 0, 0, 0);
        #pragma unroll
        for (int gg = 0; gg < 4; ++gg)
            ahi[gg] = __builtin_amdgcn_mfma_f32_16x16x32_bf16(A1, Bq[gg][1], zerov, 0, 0, 0);

        // ---- fused update: quad q -> A-row 4q (reg0), ALL 64 lanes active ----
        {
            float xv = xlds[quad][tl];
            // pre-scaled args: sigm gates hold -log2e*a, tanh gate -2log2e*a
            float a0 = fmaf(xv, wih_u[0], alo[0][0] + ahi[0][0]);
            float a1 = fmaf(xv, wih_u[1], alo[1][0] + ahi[1][0]);
            float a2 = fmaf(xv, wih_u[2], alo[2][0] + ahi[2][0]);
            float a3 = fmaf(xv, wih_u[3], alo[3][0] + ahi[3][0]);
            float ig = __builtin_amdgcn_rcpf(1.0f + __builtin_amdgcn_exp2f(a0));
            float fg = __builtin_amdgcn_rcpf(1.0f + __builtin_amdgcn_exp2f(a1));
            float gv = fmaf(2.0f, __builtin_amdgcn_rcpf(1.0f + __builtin_amdgcn_exp2f(a2)), -1.0f);
            float og = __builtin_amdgcn_rcpf(1.0f + __builtin_amdgcn_exp2f(a3));
            cc = fmaf(fg, cc, ig * gv);
            float ec = __builtin_amdgcn_exp2f(-2.8853900817779268f * cc);
            float th = fmaf(2.0f, __builtin_amdgcn_rcpf(1.0f + ec), -1.0f);
            hl = og * th;
            unsigned hp;
            asm("v_cvt_pk_bf16_f32 %0, %1, %2" : "=v"(hp) : "v"(hl), "v"(hl));
            abuf[NXT][awr] = (short)hp;
        }
        __syncthreads();   // new h-frags visible (single barrier per step)
    };

    #pragma unroll 1
    for (int tc = 0; tc < T_STEPS; tc += 2) {
        const int tl = tc & (XCH - 1);
        if (tl == 0) {
            // refill x chunk (prev barrier => old chunk fully consumed)
            if (tid < 16 * ROWS) {
                int xr = tid >> 4, tb = (tid & 15) * 8;
                const float* src = xbase + (size_t)xr * T_STEPS + tc + tb;
                float4 v0 = *(const float4*)(src);
                float4 v1 = *(const float4*)(src + 4);
                *(float4*)&xlds[xr][tb]     = v0;
                *(float4*)&xlds[xr][tb + 4] = v1;
            }
            __syncthreads();
        }
        step(std::integral_constant<int, 0>{}, tl);      // reads abuf[0], writes abuf[1]
        step(std::integral_constant<int, 1>{}, tl + 1);  // reads abuf[1], writes abuf[0]
    }

    // ---- epilogue: gather h, fc1 (relu) + fc2 ----
    hf[quad][u0] = hl;   // (row quad, unit 16w+col): 4x64 values, all lanes
    __syncthreads();

    if (w < ROWS) {
        // thread -> (row = w, unit = lane)
        float s = fc1_b[lane];
        const float4* wrow = (const float4*)(fc1_w + lane * HID);
        #pragma unroll
        for (int j4 = 0; j4 < HID / 4; ++j4) {
            float4 wv = wrow[j4];
            s = fmaf(hf[w][j4 * 4 + 0], wv.x, s);
            s = fmaf(hf[w][j4 * 4 + 1], wv.y, s);
            s = fmaf(hf[w][j4 * 4 + 2], wv.z, s);
            s = fmaf(hf[w][j4 * 4 + 3], wv.w, s);
        }
        r1buf[w][lane] = fmaxf(s, 0.0f);
    }
    __syncthreads();

    if (tid < ROWS * NCLS) {
        int m = tid / NCLS, cls = tid % NCLS;
        float s = fc2_b[cls];
        const float* w2 = fc2_w + cls * HID;
        #pragma unroll
        for (int j = 0; j < HID; ++j) s = fmaf(r1buf[m][j], w2[j], s);
        out[(size_t)(row0 + m) * NCLS + cls] = s;
    }
}

extern "C" void kernel_launch(void* const* d_in, const int* in_sizes, int n_in,
                              void* d_out, int out_size, void* d_ws, size_t ws_size,
                              hipStream_t stream) {
    const float* x     = (const float*)d_in[0];
    const float* W_ih  = (const float*)d_in[1];
    const float* W_hh  = (const float*)d_in[2];
    const float* b_ih  = (const float*)d_in[3];
    const float* b_hh  = (const float*)d_in[4];
    const float* fc1_w = (const float*)d_in[5];
    const float* fc1_b = (const float*)d_in[6];
    const float* fc2_w = (const float*)d_in[7];
    const float* fc2_b = (const float*)d_in[8];
    float* out = (float*)d_out;

    dim3 grid(256);   // 1024 rows / 4 rows per block -> 1 block per CU
    dim3 block(256);  // 4 waves (1 per SIMD)
    lstm_mfma_kernel<<<grid, block, 0, stream>>>(x, W_ih, W_hh, b_ih, b_hh,
                                                 fc1_w, fc1_b, fc2_w, fc2_b, out);
}